// Round 6
// baseline (88.100 us; speedup 1.0000x reference)
//
#include <hip/hip_runtime.h>

// NetVLAD fused via bf16 MFMA, two-stage, occupancy-optimized (4 blocks/CU).
//   s = x·W  (per-pixel 1x1 conv), a = softmax_k(s), v = a^T x + (sum a)·C
// x: [64,784,512] f32, W/C: [512,32] f32, out: [64, 512*32] f32
#define NB 64
#define HW 784
#define DD 512
#define KK 32
#define BPB 14            // blocks per batch
#define PPB 56            // pixels per block
#define CHUNK 16          // pixels per chunk (phase-C MFMA K padded 16->32 w/ zeros)
#define NCHUNK 4          // 16,16,16,8-valid

typedef __attribute__((ext_vector_type(8))) short bf16x8;   // 8 bf16 (4 VGPR)
typedef __attribute__((ext_vector_type(4))) float f32x4;    // MFMA 16x16 acc

// ws: partials [NB*BPB][4 waves][16 frags][64 lanes] float4, then asums [NB*BPB][KK]
#define PART_F   ((size_t)NB * BPB * 4 * 16 * 64 * 4)
#define ASUM_OFF PART_F
#define WS_NEED  ((PART_F + (size_t)NB * BPB * KK) * sizeof(float))

__device__ __forceinline__ unsigned short f2bf(float f) {
    unsigned u = __float_as_uint(f);
    u += 0x7fffu + ((u >> 16) & 1u);      // round-to-nearest-even
    return (unsigned short)(u >> 16);
}

template <bool USE_WS>
__global__ __launch_bounds__(256, 4) void netvlad_stage1(
    const float* __restrict__ x, const float* __restrict__ Wg,
    const float* __restrict__ Cg, float* __restrict__ out,
    float* __restrict__ ws)
{
    // total LDS ~28.8 KB -> 4 blocks/CU (16 waves/CU) with 128 VGPR
    __shared__ __align__(16) unsigned short xs[CHUNK * 520];   // 16.6 KB bf16 chunk
    __shared__ float spart[4][CHUNK][33];                      // 8.4 KB K-split partials
    __shared__ __align__(16) unsigned short aTe[KK * 40];      // a^T [k][px0..15, zeros 16..31]
    __shared__ float ared[8][KK];
    __shared__ float asumF[KK];

    const int tid = threadIdx.x;
    const int l   = tid & 63, w = tid >> 6;      // lane, wave
    const int l15 = l & 15,  lq = l >> 4;        // frag row/col, quarter
    const int k   = tid & 31, pg = tid >> 5;     // softmax mapping
    const int bid = blockIdx.x;
    const int b   = bid / BPB;
    const int pb  = (bid % BPB) * PPB;
    const float* xb = x + (size_t)b * HW * DD;

    // W B-frags in registers: Wf[ks][nt] lane holds W[d = w*128+ks*32+lq*8+j][nt*16+l15]
    bf16x8 Wf[4][2];
#pragma unroll
    for (int ks = 0; ks < 4; ++ks)
#pragma unroll
        for (int nt = 0; nt < 2; ++nt)
#pragma unroll
            for (int j = 0; j < 8; ++j)
                Wf[ks][nt][j] = (short)f2bf(Wg[(w*128 + ks*32 + lq*8 + j) * KK + nt*16 + l15]);

    f32x4 acc[2][8];   // v^T tile: [k = mt*16+lq*4+jj][d = w*128+nt*16+l15]
#pragma unroll
    for (int mt = 0; mt < 2; ++mt)
#pragma unroll
        for (int nt = 0; nt < 8; ++nt)
#pragma unroll
            for (int jj = 0; jj < 4; ++jj) acc[mt][nt][jj] = 0.f;
    float asum_part = 0.f;

    // zero aTe px-columns 16..31 once (K-pad for phase-C MFMA; stays zero all chunks)
    {
        const int zk = tid >> 3, zp = 16 + (tid & 7) * 2;
        *(unsigned*)&aTe[zk * 40 + zp] = 0u;
    }

    // synchronous chunk staging: 16 px * 512 f32 -> bf16 LDS (8 float4/thread)
    auto stageChunk = [&](int c) {
        float4 r[8];
#pragma unroll
        for (int j = 0; j < 8; ++j) {
            const int f = tid + 256*j, row = f >> 7, c4 = f & 127;
            const int p = c*CHUNK + row;
            const int gp = pb + (p < PPB ? p : PPB - 1);   // clamp pad rows
            r[j] = *(const float4*)(xb + (size_t)gp * DD + c4*4);
        }
#pragma unroll
        for (int j = 0; j < 8; ++j) {
            const int f = tid + 256*j, row = f >> 7, c4 = f & 127;
            uint2 pk = make_uint2((unsigned)f2bf(r[j].x) | ((unsigned)f2bf(r[j].y) << 16),
                                  (unsigned)f2bf(r[j].z) | ((unsigned)f2bf(r[j].w) << 16));
            *(uint2*)&xs[row*520 + c4*4] = pk;
        }
    };

    stageChunk(0);
    __syncthreads();

    for (int c = 0; c < NCHUNK; ++c) {
        // ---- phase A: s[16px][32k] partial over this wave's 128-d slice ----
        f32x4 sp[2];
#pragma unroll
        for (int nt = 0; nt < 2; ++nt)
#pragma unroll
            for (int jj = 0; jj < 4; ++jj) sp[nt][jj] = 0.f;
#pragma unroll
        for (int ks = 0; ks < 4; ++ks) {
            const bf16x8 af = *(const bf16x8*)&xs[l15*520 + w*128 + ks*32 + lq*8];
#pragma unroll
            for (int nt = 0; nt < 2; ++nt)
                sp[nt] = __builtin_amdgcn_mfma_f32_16x16x32_bf16(
                    af, Wf[ks][nt], sp[nt], 0, 0, 0);
        }
#pragma unroll
        for (int nt = 0; nt < 2; ++nt)
#pragma unroll
            for (int jj = 0; jj < 4; ++jj)
                spart[w][lq*4 + jj][nt*16 + l15] = sp[nt][jj];
        __syncthreads();

        // ---- phase B: softmax over k (no max pass: fp32 exp safe, |s| small) ----
        const int valid = (PPB - c*CHUNK < CHUNK) ? (PPB - c*CHUNK) : CHUNK;
#pragma unroll
        for (int i = 0; i < 2; ++i) {
            const int p = pg + 8*i;
            const float s = spart[0][p][k] + spart[1][p][k]
                          + spart[2][p][k] + spart[3][p][k];
            const float e = __expf(s);
            float su = e;
#pragma unroll
            for (int msk = 16; msk >= 1; msk >>= 1)
                su += __shfl_xor(su, msk);
            const float a = (p < valid) ? e / su : 0.f;
            asum_part += a;
            aTe[k*40 + p] = f2bf(a);
        }
        __syncthreads();

        // ---- phase C: v^T[32k][512d] += a^T[32k][32px] · x[32px][512d]
        //      (px 16..31 are zero in a^T; wrapped-row x garbage annihilated) ----
        bf16x8 afr[2];
#pragma unroll
        for (int mt = 0; mt < 2; ++mt)
            afr[mt] = *(const bf16x8*)&aTe[(mt*16 + l15)*40 + lq*8];
#pragma unroll
        for (int nt = 0; nt < 8; ++nt) {
            const int d = w*128 + nt*16 + l15;
            bf16x8 bfr;
#pragma unroll
            for (int j = 0; j < 8; ++j) {                  // column read of x, j rotated
                const int jj = (j + 2*lq) & 7;             // per-quarter bank stagger
                const int row = (lq*8 + jj) & 15;          // wrap px>=16 (a=0 there)
                bfr[jj] = (short)xs[row*520 + d];
            }
#pragma unroll
            for (int mt = 0; mt < 2; ++mt)
                acc[mt][nt] = __builtin_amdgcn_mfma_f32_16x16x32_bf16(
                    afr[mt], bfr, acc[mt][nt], 0, 0, 0);
        }
        __syncthreads();

        if (c + 1 < NCHUNK) {       // xs free after phase C's barrier
            stageChunk(c + 1);
            __syncthreads();
        }
    }

    // ---- block asum[k] reduce ----
    ared[pg][k] = asum_part;
    __syncthreads();
    if (tid < KK) {
        float s = 0.f;
#pragma unroll
        for (int g = 0; g < 8; ++g) s += ared[g][tid];
        if (USE_WS) ws[ASUM_OFF + (size_t)bid * KK + tid] = s;
        else        asumF[tid] = s;
    }

    if (USE_WS) {
        // partial store, thread-major: fully coalesced float4 streaming
        float4* o = (float4*)ws + ((size_t)bid * 4 + w) * (16 * 64);
#pragma unroll
        for (int mt = 0; mt < 2; ++mt)
#pragma unroll
            for (int nt = 0; nt < 8; ++nt)
                o[(mt*8 + nt)*64 + l] = make_float4(acc[mt][nt][0], acc[mt][nt][1],
                                                    acc[mt][nt][2], acc[mt][nt][3]);
    } else {
        __syncthreads();
        float* ob = out + (size_t)b * (DD * KK);
#pragma unroll
        for (int mt = 0; mt < 2; ++mt)
#pragma unroll
            for (int nt = 0; nt < 8; ++nt)
#pragma unroll
                for (int jj = 0; jj < 4; ++jj) {
                    const int kk = mt*16 + lq*4 + jj;
                    const int d  = w*128 + nt*16 + l15;
                    atomicAdd(&ob[d*KK + kk], acc[mt][nt][jj] + asumF[kk] * Cg[d*KK + kk]);
                }
    }
}

// Stage 2: block = (b, w-slice): sum 14 partials, add asum_total*C, write canonical
__global__ __launch_bounds__(256) void netvlad_stage2(
    const float* __restrict__ ws, const float* __restrict__ Cg,
    float* __restrict__ out)
{
    __shared__ float lds[128 * 33];    // canonical [d_local][k], padded
    __shared__ float asumT[KK];

    const int t = threadIdx.x;
    const int b = blockIdx.x >> 2;
    const int w = blockIdx.x & 3;

    if (t < KK) {
        float s = 0.f;
#pragma unroll
        for (int p = 0; p < BPB; ++p)
            s += ws[ASUM_OFF + (size_t)(b*BPB + p) * KK + t];
        asumT[t] = s;
    }

    const float4* wsp = (const float4*)ws;
    float4 v[4];
#pragma unroll
    for (int i = 0; i < 4; ++i) v[i] = make_float4(0.f, 0.f, 0.f, 0.f);
    for (int p = 0; p < BPB; ++p) {
        const size_t base = ((size_t)(b*BPB + p) * 4 + w) * (16 * 64);
#pragma unroll
        for (int i = 0; i < 4; ++i) {
            const float4 f4 = wsp[base + t + 256*i];
            v[i].x += f4.x; v[i].y += f4.y; v[i].z += f4.z; v[i].w += f4.w;
        }
    }
    // scatter frag layout -> canonical [d_local][k]
#pragma unroll
    for (int i = 0; i < 4; ++i) {
        const int flat = t + 256*i;
        const int f = flat >> 6, lane = flat & 63;
        const int mt = f >> 3, nt = f & 7;
        const int q = lane >> 4, r15 = lane & 15;
        const int dl = nt*16 + r15;
        const int kb = mt*16 + q*4;
        lds[dl*33 + kb + 0] = v[i].x;
        lds[dl*33 + kb + 1] = v[i].y;
        lds[dl*33 + kb + 2] = v[i].z;
        lds[dl*33 + kb + 3] = v[i].w;
    }
    __syncthreads();

    float* outw = out + (size_t)b * (DD*KK) + w * 128 * KK;
    const float* Cw = Cg + w * 128 * KK;
#pragma unroll
    for (int i = 0; i < 4; ++i) {
        const int o4 = t + 256*i;
        const int dl = o4 >> 3, kq = (o4 & 7) * 4;
        const float4 c4 = *(const float4*)&Cw[dl*KK + kq];
        float4 rr;
        rr.x = lds[dl*33 + kq + 0] + asumT[kq + 0] * c4.x;
        rr.y = lds[dl*33 + kq + 1] + asumT[kq + 1] * c4.y;
        rr.z = lds[dl*33 + kq + 2] + asumT[kq + 2] * c4.z;
        rr.w = lds[dl*33 + kq + 3] + asumT[kq + 3] * c4.w;
        ((float4*)outw)[o4] = rr;
    }
}

extern "C" void kernel_launch(void* const* d_in, const int* in_sizes, int n_in,
                              void* d_out, int out_size, void* d_ws, size_t ws_size,
                              hipStream_t stream) {
    const float* x = (const float*)d_in[0];
    const float* W = (const float*)d_in[1];
    const float* C = (const float*)d_in[2];
    float* out = (float*)d_out;

    if (ws_size >= WS_NEED) {
        float* ws = (float*)d_ws;
        netvlad_stage1<true><<<dim3(NB * BPB), dim3(256), 0, stream>>>(x, W, C, out, ws);
        netvlad_stage2<<<dim3(NB * 4), dim3(256), 0, stream>>>(ws, C, out);
    } else {
        hipMemsetAsync(out, 0, (size_t)out_size * sizeof(float), stream);
        netvlad_stage1<false><<<dim3(NB * BPB), dim3(256), 0, stream>>>(x, W, C, out, nullptr);
    }
}

// Round 7
// 70.422 us; speedup vs baseline: 1.2510x; 1.2510x over previous
//
#include <hip/hip_runtime.h>

// NetVLAD fused via bf16 MFMA, two-stage, occupancy-optimized.
//   s = x·W  (per-pixel 1x1 conv), a = softmax_k(s), v = a^T x + (sum a)·C
// x: [64,784,512] f32, W/C: [512,32] f32, out: [64, 512*32] f32
#define NB 64
#define HW 784
#define DD 512
#define KK 32
#define BPB 14            // blocks per batch
#define PPB 56            // pixels per block
#define CHUNK 16          // pixels per chunk (phase-C MFMA K padded 16->32 w/ zeros)
#define NCHUNK 4          // 16,16,16,8-valid

typedef __attribute__((ext_vector_type(8))) short bf16x8;   // 8 bf16 (4 VGPR)
typedef __attribute__((ext_vector_type(4))) float f32x4;    // MFMA 16x16 acc

// ws: partials [NB*BPB][4 waves][16 frags][64 lanes] float4, then asums [NB*BPB][KK]
#define PART_F   ((size_t)NB * BPB * 4 * 16 * 64 * 4)
#define ASUM_OFF PART_F
#define WS_NEED  ((PART_F + (size_t)NB * BPB * KK) * sizeof(float))

__device__ __forceinline__ unsigned short f2bf(float f) {
    unsigned u = __float_as_uint(f);
    u += 0x7fffu + ((u >> 16) & 1u);      // round-to-nearest-even
    return (unsigned short)(u >> 16);
}

// launch_bounds(256,2): on this toolchain arg=2 -> 128 VGPR (R5: no spill);
// arg=4 forced 64 VGPR and spilled the 64-reg accumulator (R6: +125 MB scratch).
template <bool USE_WS>
__global__ __launch_bounds__(256, 2) void netvlad_stage1(
    const float* __restrict__ x, const float* __restrict__ Wg,
    const float* __restrict__ Cg, float* __restrict__ out,
    float* __restrict__ ws)
{
    // total LDS ~28.8 KB; with 128 VGPR -> 4 blocks/CU (16 waves/CU)
    __shared__ __align__(16) unsigned short xs[CHUNK * 520];   // 16.6 KB bf16 chunk
    __shared__ float spart[4][CHUNK][33];                      // 8.4 KB K-split partials
    __shared__ __align__(16) unsigned short aTe[KK * 40];      // a^T [k][px0..15, zeros 16..31]
    __shared__ float ared[8][KK];
    __shared__ float asumF[KK];

    const int tid = threadIdx.x;
    const int l   = tid & 63, w = tid >> 6;      // lane, wave
    const int l15 = l & 15,  lq = l >> 4;        // frag row/col, quarter
    const int k   = tid & 31, pg = tid >> 5;     // softmax mapping
    const int bid = blockIdx.x;
    const int b   = bid / BPB;
    const int pb  = (bid % BPB) * PPB;
    const float* xb = x + (size_t)b * HW * DD;

    // W B-frags in registers: Wf[ks][nt] lane holds W[d = w*128+ks*32+lq*8+j][nt*16+l15]
    bf16x8 Wf[4][2];
#pragma unroll
    for (int ks = 0; ks < 4; ++ks)
#pragma unroll
        for (int nt = 0; nt < 2; ++nt)
#pragma unroll
            for (int j = 0; j < 8; ++j)
                Wf[ks][nt][j] = (short)f2bf(Wg[(w*128 + ks*32 + lq*8 + j) * KK + nt*16 + l15]);

    f32x4 acc[2][8];   // v^T tile: [k = mt*16+lq*4+jj][d = w*128+nt*16+l15]
#pragma unroll
    for (int mt = 0; mt < 2; ++mt)
#pragma unroll
        for (int nt = 0; nt < 8; ++nt)
#pragma unroll
            for (int jj = 0; jj < 4; ++jj) acc[mt][nt][jj] = 0.f;
    float asum_part = 0.f;

    // zero aTe px-columns 16..31 once (K-pad for phase-C MFMA; stays zero all chunks)
    {
        const int zk = tid >> 3, zp = 16 + (tid & 7) * 2;
        *(unsigned*)&aTe[zk * 40 + zp] = 0u;
    }

    // synchronous chunk staging: 16 px * 512 f32 -> bf16 LDS (8 float4/thread)
    auto stageChunk = [&](int c) {
        float4 r[8];
#pragma unroll
        for (int j = 0; j < 8; ++j) {
            const int f = tid + 256*j, row = f >> 7, c4 = f & 127;
            const int p = c*CHUNK + row;
            const int gp = pb + (p < PPB ? p : PPB - 1);   // clamp pad rows
            r[j] = *(const float4*)(xb + (size_t)gp * DD + c4*4);
        }
#pragma unroll
        for (int j = 0; j < 8; ++j) {
            const int f = tid + 256*j, row = f >> 7, c4 = f & 127;
            uint2 pk = make_uint2((unsigned)f2bf(r[j].x) | ((unsigned)f2bf(r[j].y) << 16),
                                  (unsigned)f2bf(r[j].z) | ((unsigned)f2bf(r[j].w) << 16));
            *(uint2*)&xs[row*520 + c4*4] = pk;
        }
    };

    stageChunk(0);
    __syncthreads();

    for (int c = 0; c < NCHUNK; ++c) {
        // ---- phase A: s[16px][32k] partial over this wave's 128-d slice ----
        f32x4 sp[2];
#pragma unroll
        for (int nt = 0; nt < 2; ++nt)
#pragma unroll
            for (int jj = 0; jj < 4; ++jj) sp[nt][jj] = 0.f;
#pragma unroll
        for (int ks = 0; ks < 4; ++ks) {
            const bf16x8 af = *(const bf16x8*)&xs[l15*520 + w*128 + ks*32 + lq*8];
#pragma unroll
            for (int nt = 0; nt < 2; ++nt)
                sp[nt] = __builtin_amdgcn_mfma_f32_16x16x32_bf16(
                    af, Wf[ks][nt], sp[nt], 0, 0, 0);
        }
#pragma unroll
        for (int nt = 0; nt < 2; ++nt)
#pragma unroll
            for (int jj = 0; jj < 4; ++jj)
                spart[w][lq*4 + jj][nt*16 + l15] = sp[nt][jj];
        __syncthreads();

        // ---- phase B: softmax over k (no max pass: fp32 exp safe, |s| small) ----
        const int valid = (PPB - c*CHUNK < CHUNK) ? (PPB - c*CHUNK) : CHUNK;
#pragma unroll
        for (int i = 0; i < 2; ++i) {
            const int p = pg + 8*i;
            const float s = spart[0][p][k] + spart[1][p][k]
                          + spart[2][p][k] + spart[3][p][k];
            const float e = __expf(s);
            float su = e;
#pragma unroll
            for (int msk = 16; msk >= 1; msk >>= 1)
                su += __shfl_xor(su, msk);
            const float a = (p < valid) ? e / su : 0.f;
            asum_part += a;
            aTe[k*40 + p] = f2bf(a);
        }
        __syncthreads();

        // ---- phase C: v^T[32k][512d] += a^T[32k][32px] · x[32px][512d]
        //      (px 16..31 are zero in a^T; wrapped-row x garbage annihilated) ----
        bf16x8 afr[2];
#pragma unroll
        for (int mt = 0; mt < 2; ++mt)
            afr[mt] = *(const bf16x8*)&aTe[(mt*16 + l15)*40 + lq*8];
#pragma unroll
        for (int nt = 0; nt < 8; ++nt) {
            const int d = w*128 + nt*16 + l15;
            bf16x8 bfr;
#pragma unroll
            for (int j = 0; j < 8; ++j) {                  // column read of x, j rotated
                const int jj = (j + 2*lq) & 7;             // per-quarter bank stagger
                const int row = (lq*8 + jj) & 15;          // wrap px>=16 (a=0 there)
                bfr[jj] = (short)xs[row*520 + d];
            }
#pragma unroll
            for (int mt = 0; mt < 2; ++mt)
                acc[mt][nt] = __builtin_amdgcn_mfma_f32_16x16x32_bf16(
                    afr[mt], bfr, acc[mt][nt], 0, 0, 0);
        }
        __syncthreads();

        if (c + 1 < NCHUNK) {       // xs free after phase C's barrier
            stageChunk(c + 1);
            __syncthreads();
        }
    }

    // ---- block asum[k] reduce ----
    ared[pg][k] = asum_part;
    __syncthreads();
    if (tid < KK) {
        float s = 0.f;
#pragma unroll
        for (int g = 0; g < 8; ++g) s += ared[g][tid];
        if (USE_WS) ws[ASUM_OFF + (size_t)bid * KK + tid] = s;
        else        asumF[tid] = s;
    }

    if (USE_WS) {
        // partial store, thread-major: fully coalesced float4 streaming
        float4* o = (float4*)ws + ((size_t)bid * 4 + w) * (16 * 64);
#pragma unroll
        for (int mt = 0; mt < 2; ++mt)
#pragma unroll
            for (int nt = 0; nt < 8; ++nt)
                o[(mt*8 + nt)*64 + l] = make_float4(acc[mt][nt][0], acc[mt][nt][1],
                                                    acc[mt][nt][2], acc[mt][nt][3]);
    } else {
        __syncthreads();
        float* ob = out + (size_t)b * (DD * KK);
#pragma unroll
        for (int mt = 0; mt < 2; ++mt)
#pragma unroll
            for (int nt = 0; nt < 8; ++nt)
#pragma unroll
                for (int jj = 0; jj < 4; ++jj) {
                    const int kk = mt*16 + lq*4 + jj;
                    const int d  = w*128 + nt*16 + l15;
                    atomicAdd(&ob[d*KK + kk], acc[mt][nt][jj] + asumF[kk] * Cg[d*KK + kk]);
                }
    }
}

// Stage 2: block = (b, w-slice): sum 14 partials, add asum_total*C, write canonical
__global__ __launch_bounds__(256) void netvlad_stage2(
    const float* __restrict__ ws, const float* __restrict__ Cg,
    float* __restrict__ out)
{
    __shared__ float lds[128 * 33];    // canonical [d_local][k], padded
    __shared__ float asumT[KK];

    const int t = threadIdx.x;
    const int b = blockIdx.x >> 2;
    const int w = blockIdx.x & 3;

    if (t < KK) {
        float s = 0.f;
#pragma unroll
        for (int p = 0; p < BPB; ++p)
            s += ws[ASUM_OFF + (size_t)(b*BPB + p) * KK + t];
        asumT[t] = s;
    }

    const float4* wsp = (const float4*)ws;
    float4 v[4];
#pragma unroll
    for (int i = 0; i < 4; ++i) v[i] = make_float4(0.f, 0.f, 0.f, 0.f);
    for (int p = 0; p < BPB; ++p) {
        const size_t base = ((size_t)(b*BPB + p) * 4 + w) * (16 * 64);
#pragma unroll
        for (int i = 0; i < 4; ++i) {
            const float4 f4 = wsp[base + t + 256*i];
            v[i].x += f4.x; v[i].y += f4.y; v[i].z += f4.z; v[i].w += f4.w;
        }
    }
    // scatter frag layout -> canonical [d_local][k]
#pragma unroll
    for (int i = 0; i < 4; ++i) {
        const int flat = t + 256*i;
        const int f = flat >> 6, lane = flat & 63;
        const int mt = f >> 3, nt = f & 7;
        const int q = lane >> 4, r15 = lane & 15;
        const int dl = nt*16 + r15;
        const int kb = mt*16 + q*4;
        lds[dl*33 + kb + 0] = v[i].x;
        lds[dl*33 + kb + 1] = v[i].y;
        lds[dl*33 + kb + 2] = v[i].z;
        lds[dl*33 + kb + 3] = v[i].w;
    }
    __syncthreads();

    float* outw = out + (size_t)b * (DD*KK) + w * 128 * KK;
    const float* Cw = Cg + w * 128 * KK;
#pragma unroll
    for (int i = 0; i < 4; ++i) {
        const int o4 = t + 256*i;
        const int dl = o4 >> 3, kq = (o4 & 7) * 4;
        const float4 c4 = *(const float4*)&Cw[dl*KK + kq];
        float4 rr;
        rr.x = lds[dl*33 + kq + 0] + asumT[kq + 0] * c4.x;
        rr.y = lds[dl*33 + kq + 1] + asumT[kq + 1] * c4.y;
        rr.z = lds[dl*33 + kq + 2] + asumT[kq + 2] * c4.z;
        rr.w = lds[dl*33 + kq + 3] + asumT[kq + 3] * c4.w;
        ((float4*)outw)[o4] = rr;
    }
}

extern "C" void kernel_launch(void* const* d_in, const int* in_sizes, int n_in,
                              void* d_out, int out_size, void* d_ws, size_t ws_size,
                              hipStream_t stream) {
    const float* x = (const float*)d_in[0];
    const float* W = (const float*)d_in[1];
    const float* C = (const float*)d_in[2];
    float* out = (float*)d_out;

    if (ws_size >= WS_NEED) {
        float* ws = (float*)d_ws;
        netvlad_stage1<true><<<dim3(NB * BPB), dim3(256), 0, stream>>>(x, W, C, out, ws);
        netvlad_stage2<<<dim3(NB * 4), dim3(256), 0, stream>>>(ws, C, out);
    } else {
        hipMemsetAsync(out, 0, (size_t)out_size * sizeof(float), stream);
        netvlad_stage1<false><<<dim3(NB * BPB), dim3(256), 0, stream>>>(x, W, C, out, nullptr);
    }
}

// Round 8
// 59.428 us; speedup vs baseline: 1.4825x; 1.1850x over previous
//
#include <hip/hip_runtime.h>

// NetVLAD fused via bf16 MFMA, two-stage, 8-wave blocks.
//   s = x·W  (per-pixel 1x1 conv), a = softmax_k(s), v = a^T x + (sum a)·C
// x: [64,784,512] f32, W/C: [512,32] f32, out: [64, 512*32] f32
#define NB 64
#define HW 784
#define DD 512
#define KK 32
#define BPB 14            // blocks per batch
#define PPB 56            // pixels per block
#define CHUNK 32          // pixels per chunk (chunk 1: 24 valid + 8 clamp/a=0)
#define NCHUNK 2

typedef __attribute__((ext_vector_type(8))) short bf16x8;   // 8 bf16 (4 VGPR)
typedef __attribute__((ext_vector_type(4))) float f32x4;    // MFMA 16x16 acc

// ws: partials [NB*BPB][8 waves][8 frags][64 lanes] float4, then asums [NB*BPB][KK]
#define PART_F   ((size_t)NB * BPB * 8 * 8 * 64 * 4)
#define ASUM_OFF PART_F
#define WS_NEED  ((PART_F + (size_t)NB * BPB * KK) * sizeof(float))

__device__ __forceinline__ unsigned short f2bf(float f) {
    unsigned u = __float_as_uint(f);
    u += 0x7fffu + ((u >> 16) & 1u);      // round-to-nearest-even
    return (unsigned short)(u >> 16);
}

template <bool USE_WS>
__global__ __launch_bounds__(512) void netvlad_stage1(
    const float* __restrict__ x, const float* __restrict__ Wg,
    const float* __restrict__ Cg, float* __restrict__ out,
    float* __restrict__ ws)
{
    // LDS total ~51.6 KB
    __shared__ __align__(16) unsigned short xs[CHUNK * 520];   // 33.3 KB bf16 chunk
    __shared__ float spart[4][CHUNK][33];                      // 16.9 KB d-split partials
    __shared__ __align__(16) unsigned short aTe[KK * 40];      // a^T [k][px] (2.56 KB)
    __shared__ float asumF[KK];

    const int tid = threadIdx.x;
    const int l   = tid & 63, w = tid >> 6;      // lane, wave 0..7
    const int l15 = l & 15,  lq = l >> 4;        // frag row/col, quarter
    const int d4  = w & 3;                        // phase-A d-slice 128*d4
    const int pgrp= w >> 2;                       // phase-A px-group (16 px)
    const int k   = tid & 31, pg = tid >> 5;     // softmax mapping: pg 0..15
    const int bid = blockIdx.x;
    const int b   = bid / BPB;
    const int pb  = (bid % BPB) * PPB;
    const float* xb = x + (size_t)b * HW * DD;

    // W B-frags: Wf[ks][nt] lane holds W[d = d4*128+ks*32+lq*8+j][nt*16+l15]
    bf16x8 Wf[4][2];
#pragma unroll
    for (int ks = 0; ks < 4; ++ks)
#pragma unroll
        for (int nt = 0; nt < 2; ++nt)
#pragma unroll
            for (int j = 0; j < 8; ++j)
                Wf[ks][nt][j] = (short)f2bf(Wg[(d4*128 + ks*32 + lq*8 + j) * KK + nt*16 + l15]);

    // phase-C: wave owns d-slice [64w, 64w+64): acc[mt][nt] -> k=mt*16+lq*4+jj, d=64w+nt*16+l15
    f32x4 acc[2][4];
#pragma unroll
    for (int mt = 0; mt < 2; ++mt)
#pragma unroll
        for (int nt = 0; nt < 4; ++nt)
#pragma unroll
            for (int jj = 0; jj < 4; ++jj) acc[mt][nt][jj] = 0.f;
    float asum_part = 0.f;

    // synchronous chunk staging: 32 px * 512 f32 -> bf16 LDS (8 float4/thread)
    auto stageChunk = [&](int c) {
        float4 r[8];
#pragma unroll
        for (int j = 0; j < 8; ++j) {
            const int f = tid + 512*j, row = f >> 7, c4 = f & 127;
            const int p = c*CHUNK + row;
            const int gp = pb + (p < PPB ? p : PPB - 1);   // clamp pad rows
            r[j] = *(const float4*)(xb + (size_t)gp * DD + c4*4);
        }
#pragma unroll
        for (int j = 0; j < 8; ++j) {
            const int f = tid + 512*j, row = f >> 7, c4 = f & 127;
            uint2 pk = make_uint2((unsigned)f2bf(r[j].x) | ((unsigned)f2bf(r[j].y) << 16),
                                  (unsigned)f2bf(r[j].z) | ((unsigned)f2bf(r[j].w) << 16));
            *(uint2*)&xs[row*520 + c4*4] = pk;
        }
    };

    stageChunk(0);
    __syncthreads();

    for (int c = 0; c < NCHUNK; ++c) {
        // ---- phase A: s[16px(pgrp)][32k] partial over d-slice 128*d4 ----
        f32x4 sp[2];
#pragma unroll
        for (int nt = 0; nt < 2; ++nt)
#pragma unroll
            for (int jj = 0; jj < 4; ++jj) sp[nt][jj] = 0.f;
#pragma unroll
        for (int ks = 0; ks < 4; ++ks) {
            const bf16x8 af = *(const bf16x8*)&xs[(pgrp*16 + l15)*520 + d4*128 + ks*32 + lq*8];
#pragma unroll
            for (int nt = 0; nt < 2; ++nt)
                sp[nt] = __builtin_amdgcn_mfma_f32_16x16x32_bf16(
                    af, Wf[ks][nt], sp[nt], 0, 0, 0);
        }
#pragma unroll
        for (int nt = 0; nt < 2; ++nt)
#pragma unroll
            for (int jj = 0; jj < 4; ++jj)
                spart[d4][pgrp*16 + lq*4 + jj][nt*16 + l15] = sp[nt][jj];
        __syncthreads();

        // ---- phase B: softmax over k; thread (pg,k), px = pg + 16i ----
        const int valid = (PPB - c*CHUNK < CHUNK) ? (PPB - c*CHUNK) : CHUNK;
#pragma unroll
        for (int i = 0; i < 2; ++i) {
            const int p = pg + 16*i;
            const float s = spart[0][p][k] + spart[1][p][k]
                          + spart[2][p][k] + spart[3][p][k];
            const float e = __expf(s);
            float su = e;
#pragma unroll
            for (int msk = 16; msk >= 1; msk >>= 1)
                su += __shfl_xor(su, msk);
            const float a = (p < valid) ? e * __builtin_amdgcn_rcpf(su) : 0.f;
            asum_part += a;
            aTe[k*40 + p] = f2bf(a);
        }
        __syncthreads();

        // ---- phase C: v^T[32k][64d-slice] += a^T[32k][32px] · x[32px][d] ----
        bf16x8 afr[2];
#pragma unroll
        for (int mt = 0; mt < 2; ++mt)
            afr[mt] = *(const bf16x8*)&aTe[(mt*16 + l15)*40 + lq*8];
#pragma unroll
        for (int nt = 0; nt < 4; ++nt) {
            const int d = w*64 + nt*16 + l15;
            bf16x8 bfr;
#pragma unroll
            for (int j = 0; j < 8; ++j) {                  // column read of x, j rotated
                const int jj = (j + 2*lq) & 7;             // per-quarter bank stagger
                bfr[jj] = (short)xs[(lq*8 + jj)*520 + d];
            }
#pragma unroll
            for (int mt = 0; mt < 2; ++mt)
                acc[mt][nt] = __builtin_amdgcn_mfma_f32_16x16x32_bf16(
                    afr[mt], bfr, acc[mt][nt], 0, 0, 0);
        }
        __syncthreads();

        if (c + 1 < NCHUNK) {       // xs free after phase C's barrier
            stageChunk(c + 1);
            __syncthreads();
        }
    }

    // ---- block asum[k] reduce (ared aliases aTe: dead after last phase C) ----
    float* ared = (float*)aTe;     // [16][32]
    ared[pg*KK + k] = asum_part;
    __syncthreads();
    if (tid < KK) {
        float s = 0.f;
#pragma unroll
        for (int g = 0; g < 16; ++g) s += ared[g*KK + tid];
        if (USE_WS) ws[ASUM_OFF + (size_t)bid * KK + tid] = s;
        else        asumF[tid] = s;
    }

    if (USE_WS) {
        // partial store, thread-major: fully coalesced float4 streaming
        float4* o = (float4*)ws + ((size_t)bid * 8 + w) * (8 * 64);
#pragma unroll
        for (int mt = 0; mt < 2; ++mt)
#pragma unroll
            for (int nt = 0; nt < 4; ++nt)
                o[(mt*4 + nt)*64 + l] = make_float4(acc[mt][nt][0], acc[mt][nt][1],
                                                    acc[mt][nt][2], acc[mt][nt][3]);
    } else {
        __syncthreads();
        float* ob = out + (size_t)b * (DD * KK);
#pragma unroll
        for (int mt = 0; mt < 2; ++mt)
#pragma unroll
            for (int nt = 0; nt < 4; ++nt)
#pragma unroll
                for (int jj = 0; jj < 4; ++jj) {
                    const int kk = mt*16 + lq*4 + jj;
                    const int d  = w*64 + nt*16 + l15;
                    atomicAdd(&ob[d*KK + kk], acc[mt][nt][jj] + asumF[kk] * Cg[d*KK + kk]);
                }
    }
}

// Stage 2: block = (b, 128-d slice): sum 14 partials, add asum_total*C, write canonical
__global__ __launch_bounds__(256) void netvlad_stage2(
    const float* __restrict__ ws, const float* __restrict__ Cg,
    float* __restrict__ out)
{
    __shared__ float lds[128 * 33];    // canonical [d_local][k], padded
    __shared__ float asumT[KK];

    const int t = threadIdx.x;
    const int b = blockIdx.x >> 2;
    const int jsl = blockIdx.x & 3;    // d-slice [128*jsl, +128) = stage1 waves {2jsl, 2jsl+1}

    if (t < KK) {
        float s = 0.f;
#pragma unroll
        for (int p = 0; p < BPB; ++p)
            s += ws[ASUM_OFF + (size_t)(b*BPB + p) * KK + t];
        asumT[t] = s;
    }

    const float4* wsp = (const float4*)ws;
    float4 v[4];
#pragma unroll
    for (int i = 0; i < 4; ++i) v[i] = make_float4(0.f, 0.f, 0.f, 0.f);
    for (int p = 0; p < BPB; ++p) {
        const size_t base = (size_t)(b*BPB + p) * 8 * (8 * 64);
#pragma unroll
        for (int i = 0; i < 4; ++i) {
            const int flat = t + 256*i;           // (w2, fr, lane)
            const int g = flat >> 6, lane = flat & 63;
            const int w2 = g >> 3, fr = g & 7;
            const float4 f4 = wsp[base + ((size_t)(2*jsl + w2) * 8 + fr)*64 + lane];
            v[i].x += f4.x; v[i].y += f4.y; v[i].z += f4.z; v[i].w += f4.w;
        }
    }
    // scatter frag layout -> canonical [d_local][k]
#pragma unroll
    for (int i = 0; i < 4; ++i) {
        const int flat = t + 256*i;
        const int g = flat >> 6, lane = flat & 63;
        const int w2 = g >> 3, fr = g & 7;
        const int mt = fr >> 2, nt = fr & 3;
        const int q = lane >> 4, r15 = lane & 15;
        const int dl = w2*64 + nt*16 + r15;
        const int kb = mt*16 + q*4;
        lds[dl*33 + kb + 0] = v[i].x;
        lds[dl*33 + kb + 1] = v[i].y;
        lds[dl*33 + kb + 2] = v[i].z;
        lds[dl*33 + kb + 3] = v[i].w;
    }
    __syncthreads();

    float* outw = out + (size_t)b * (DD*KK) + jsl * 128 * KK;
    const float* Cw = Cg + jsl * 128 * KK;
#pragma unroll
    for (int i = 0; i < 4; ++i) {
        const int o4 = t + 256*i;
        const int dl = o4 >> 3, kq = (o4 & 7) * 4;
        const float4 c4 = *(const float4*)&Cw[dl*KK + kq];
        float4 rr;
        rr.x = lds[dl*33 + kq + 0] + asumT[kq + 0] * c4.x;
        rr.y = lds[dl*33 + kq + 1] + asumT[kq + 1] * c4.y;
        rr.z = lds[dl*33 + kq + 2] + asumT[kq + 2] * c4.z;
        rr.w = lds[dl*33 + kq + 3] + asumT[kq + 3] * c4.w;
        ((float4*)outw)[o4] = rr;
    }
}

extern "C" void kernel_launch(void* const* d_in, const int* in_sizes, int n_in,
                              void* d_out, int out_size, void* d_ws, size_t ws_size,
                              hipStream_t stream) {
    const float* x = (const float*)d_in[0];
    const float* W = (const float*)d_in[1];
    const float* C = (const float*)d_in[2];
    float* out = (float*)d_out;

    if (ws_size >= WS_NEED) {
        float* ws = (float*)d_ws;
        netvlad_stage1<true><<<dim3(NB * BPB), dim3(512), 0, stream>>>(x, W, C, out, ws);
        netvlad_stage2<<<dim3(NB * 4), dim3(256), 0, stream>>>(ws, C, out);
    } else {
        hipMemsetAsync(out, 0, (size_t)out_size * sizeof(float), stream);
        netvlad_stage1<false><<<dim3(NB * BPB), dim3(512), 0, stream>>>(x, W, C, out, nullptr);
    }
}